// Round 13
// baseline (236.747 us; speedup 1.0000x reference)
//
#include <hip/hip_runtime.h>

#define HW 16384   // 128*128

typedef __attribute__((ext_vector_type(8))) short short8;
typedef __attribute__((ext_vector_type(16))) float floatx16;
typedef __attribute__((ext_vector_type(4))) unsigned int uvec4;

__device__ inline unsigned short f2bf(float f) {
    unsigned u = __builtin_bit_cast(unsigned, f);
    u = (u + 0x7FFFu + ((u >> 16) & 1u)) >> 16;   // RNE
    return (unsigned short)u;
}

// pack two fp32 -> bf16x2 by truncation: one v_perm_b32
__device__ inline unsigned pack_bf_trunc(float lo, float hi) {
    return __builtin_amdgcn_perm(__builtin_bit_cast(unsigned, hi),
                                 __builtin_bit_cast(unsigned, lo), 0x07060302u);
}

__device__ inline unsigned short trunc_bf(float f) {
    return (unsigned short)(__builtin_bit_cast(unsigned, f) >> 16);
}

// ---------------------------------------------------------------------------
// Cast + transpose x: [b][c][p] fp32 -> xt[b][p][c] bf16 (coalesced only).
// Folds the W-cast into 80 of the 4096 blocks: Wb[320][256] bf16,
// rows 0-31 q (PRE-SCALED by log2e), 32-63 k, 64-319 v.
// ---------------------------------------------------------------------------
__global__ __launch_bounds__(256) void cast_xt_kernel(
    const float* __restrict__ x,
    const float* __restrict__ Wq, const float* __restrict__ Wk,
    const float* __restrict__ Wv, unsigned short* __restrict__ Wb,
    unsigned short* __restrict__ xt)
{
    __shared__ unsigned short T[64][66];
    const int tid = threadIdx.x;
    const int p0 = blockIdx.x * 64;
    const int c0 = blockIdx.y * 64;
    const int b  = blockIdx.z;

    if (b == 0 && blockIdx.y == 0 && blockIdx.x < 80) {   // folded castW
        int e0 = (blockIdx.x * 256 + tid) * 4;
        int row = e0 >> 8, col = e0 & 255;
        const float* src = (row < 32) ? (Wq + row * 256 + col)
                         : (row < 64) ? (Wk + (row - 32) * 256 + col)
                                      : (Wv + (row - 64) * 256 + col);
        float4 v = *(const float4*)src;
        if (row < 32) {   // q rows: fold log2(e)
            const float L2E = 1.4426950408889634f;
            v.x *= L2E; v.y *= L2E; v.z *= L2E; v.w *= L2E;
        }
        uint2 pk;
        pk.x = f2bf(v.x) | ((unsigned)f2bf(v.y) << 16);
        pk.y = f2bf(v.z) | ((unsigned)f2bf(v.w) << 16);
        *(uint2*)&Wb[e0] = pk;
    }

    #pragma unroll
    for (int i = 0; i < 4; i++) {
        int e = i * 256 + tid;
        int c = e >> 4, seg = e & 15;
        float4 v = *(const float4*)&x[((b * 256 + c0 + c) << 14) + p0 + seg * 4];
        ((unsigned*)&T[c][seg * 4])[0] = f2bf(v.x) | ((unsigned)f2bf(v.y) << 16);
        ((unsigned*)&T[c][seg * 4])[1] = f2bf(v.z) | ((unsigned)f2bf(v.w) << 16);
    }
    __syncthreads();
    #pragma unroll
    for (int i = 0; i < 2; i++) {
        int e = i * 256 + tid;
        int p = e >> 3, cs = e & 7;
        unsigned short t[8];
        #pragma unroll
        for (int j = 0; j < 8; j++) t[j] = T[cs * 8 + j][p];
        uint4 pk;
        pk.x = t[0] | ((unsigned)t[1] << 16);
        pk.y = t[2] | ((unsigned)t[3] << 16);
        pk.z = t[4] | ((unsigned)t[5] << 16);
        pk.w = t[6] | ((unsigned)t[7] << 16);
        *(uint4*)&xt[(((b << 14) + p0 + p) << 8) + c0 + cs * 8] = pk;
    }
}

// ---------------------------------------------------------------------------
// Pixel-record transpose xt -> xtc: record = 512B (256ch bf16).
// Block (x0, b): reads 128 records xt[y*128+x0] (512B contiguous each,
// 64KB stride), writes xtc[x0*128+y] = one CONTIGUOUS 64KB run.
// ---------------------------------------------------------------------------
__global__ __launch_bounds__(256) void tpx_kernel(
    const unsigned short* __restrict__ xt, unsigned short* __restrict__ xtc)
{
    const int x0 = blockIdx.x;    // 0..127
    const int b  = blockIdx.y;    // 0..3
    const int tid = threadIdx.x;
    const int r = tid >> 5, cseg = tid & 31;   // 8 records / iteration
    #pragma unroll
    for (int i = 0; i < 16; i++) {
        int y = i * 8 + r;
        uint4 v = *(const uint4*)&xt[(((b << 14) + y * 128 + x0) << 8) + cseg * 8];
        *(uint4*)&xtc[(((b << 14) + x0 * 128 + y) << 8) + cseg * 8] = v;
    }
}

// ---------------------------------------------------------------------------
// FUSED proj+attention v8 = R12 v7 + T14 async-STAGE split:
// the xt-panel chunk for phase kc+1 is loaded into REGISTERS (xreg[4]) before
// phase kc's MFMA section, so the global L2/HBM latency (~300-900cy) flies
// under the MFMA phase instead of sitting exposed between the two barriers
// (R12: 16 phases x exposed global round-trip was the dominant stall at
// MfmaUtil 16.6%, 89us vs ~25us floor). Between barriers: only 4 ds_writes.
// Cross-side prefetch: side-1's kc0 chunk loads during side-0's attention.
// Ws / Vs / Kl / extract / attention / epilogue identical to R12 (verified
// absmax 0.047). LDS ~76KB -> 2 blocks/CU; VGPR +16 (xreg).
// ---------------------------------------------------------------------------
__global__ __launch_bounds__(256, 2) void fused_kernel(
    const unsigned short* __restrict__ Wb, const unsigned short* __restrict__ xt,
    const unsigned short* __restrict__ xtc,
    const float* __restrict__ bq, const float* __restrict__ bk,
    const float* __restrict__ bv,
    const float* __restrict__ xin, const float* __restrict__ gamma,
    float* __restrict__ out)
{
    __shared__ __align__(16) unsigned short Ws[80 * 256];    // 40KB W rows
    __shared__ __align__(16) unsigned short XTS[128 * 64];   // 16KB xt panel
    __shared__ __align__(16) unsigned short Vs[64 * 128];    // 16KB [ch][key]
    __shared__ __align__(16) unsigned short Kl[128 * 8];     // 2KB [px][8ch]
    __shared__ float biasS[80];                              // q8|k8|v64

    const int tid = threadIdx.x;
    // XCD chunk swizzle: XCD k owns y in [16k,16k+16), all 16 bh per y.
    const int logical = (blockIdx.x & 7) * 256 + (blockIdx.x >> 3);
    const int bh = logical & 15, y = logical >> 4;
    const int b = bh >> 2, h = bh & 3;
    const int w = tid >> 6, l = tid & 63, lr = l & 31, lh = l >> 5;
    const int px = 32 * w + lr;

    if (tid < 80) biasS[tid] = (tid < 8)  ? bq[h * 8 + tid] * 1.4426950408889634f
                             : (tid < 16) ? bk[h * 8 + tid - 8]
                                          : bv[h * 64 + tid - 16];

    // stage W rows: local [0-7]=q(h), [8-15]=k(h), [16-79]=v(h); chunk^=(R&7)
    #pragma unroll
    for (int i = 0; i < 10; i++) {
        int e = i * 256 + tid;            // 2560 chunk-copies of 16B
        int R = e >> 5, c = e & 31, cp = c ^ (R & 7);
        int gr = (R < 8)  ? h * 8 + R
               : (R < 16) ? 32 + h * 8 + (R - 8)
                          : 64 + h * 64 + (R - 16);
        *(uint4*)&Ws[R * 256 + cp * 8] = *(const uint4*)&Wb[gr * 256 + c * 8];
    }

    // pixel-panel bases (shorts): both sides are contiguous 64KB panels
    const unsigned short* base0 = xt  + ((((b << 14) + y * 128)) << 8);
    const unsigned short* base1 = xtc + ((((b << 14) + y * 128)) << 8);

    floatx16 z16 = {0,0,0,0,0,0,0,0,0,0,0,0,0,0,0,0};
    short8 z8 = {0,0,0,0,0,0,0,0};
    floatx16 oh0 = z16, oh1 = z16, ov0 = z16, ov1 = z16;
    float ssA = 1.0f, ssB = 1.0f;

    // T14 stage-ahead registers (static-indexed via full unroll, rule #20)
    uint4 xreg[4];
    #pragma unroll
    for (int i = 0; i < 4; i++) {          // preload side0 kc0
        int e = i * 256 + tid, row = e >> 3, seg = e & 7;
        xreg[i] = *(const uint4*)&base0[(row << 8) + seg * 8];
    }

    #pragma unroll
    for (int side = 0; side < 2; side++) {
        // ---------------- projection: K=256 reduction ----------------
        floatx16 a0 = z16, a1 = z16, a2 = z16;
        for (int kc = 0; kc < 4; kc++) {
            __syncthreads();   // all waves done reading XTS (prev MFMA phase)
            // drain staged regs -> XTS (swizzled); fast LDS-only section
            #pragma unroll
            for (int i = 0; i < 4; i++) {
                int e = i * 256 + tid, row = e >> 3, seg = e & 7, cp = seg ^ (row & 7);
                *(uint4*)&XTS[row * 64 + cp * 8] = xreg[i];
            }
            // issue next chunk's global loads: they fly under the MFMA phase
            if (kc < 3) {
                const unsigned short* bs = side ? base1 : base0;
                #pragma unroll
                for (int i = 0; i < 4; i++) {
                    int e = i * 256 + tid, row = e >> 3, seg = e & 7;
                    xreg[i] = *(const uint4*)&bs[(row << 8) + (kc + 1) * 64 + seg * 8];
                }
            } else if (side == 0) {        // cross-side prefetch (flies under attn0 too)
                #pragma unroll
                for (int i = 0; i < 4; i++) {
                    int e = i * 256 + tid, row = e >> 3, seg = e & 7;
                    xreg[i] = *(const uint4*)&base1[(row << 8) + seg * 8];
                }
            }
            __syncthreads();   // XTS visible
            #pragma unroll
            for (int ks = 0; ks < 4; ks++) {   // full 64ch per kc
                int cx = ((2 * ks + lh) ^ (lr & 7)) * 8;
                short8 bfr = *(const short8*)&XTS[px * 64 + cx];
                int ci = kc * 8 + 2 * ks + lh;
                int cwp = (ci ^ (lr & 7)) * 8;
                short8 af0 = *(const short8*)&Ws[lr * 256 + cwp];
                short8 af1 = *(const short8*)&Ws[(32 + lr) * 256 + cwp];
                short8 af2 = *(const short8*)&Ws[(64 + (lr & 15)) * 256 + cwp];
                a0 = __builtin_amdgcn_mfma_f32_32x32x16_bf16(af0, bfr, a0, 0, 0, 0);
                a1 = __builtin_amdgcn_mfma_f32_32x32x16_bf16(af1, bfr, a1, 0, 0, 0);
                a2 = __builtin_amdgcn_mfma_f32_32x32x16_bf16(af2, bfr, a2, 0, 0, 0);
            }
        }
        // ---------------- extract q / k / v ----------------
        // q: tile0 rows 0-7 = regs 0-3 (+4lh). lh=0 lane needs ch0-7:
        // words = [own(ch 0-3), partner(ch 4-7)] via shfl_xor(32).
        unsigned X0 = pack_bf_trunc(a0[0] + biasS[4 * lh + 0], a0[1] + biasS[4 * lh + 1]);
        unsigned X1 = pack_bf_trunc(a0[2] + biasS[4 * lh + 2], a0[3] + biasS[4 * lh + 3]);
        unsigned pX0 = __shfl_xor(X0, 32), pX1 = __shfl_xor(X1, 32);
        short8 bfq = z8;
        if (lh == 0) {
            uvec4 t; t.x = X0; t.y = X1; t.z = pX0; t.w = pX1;
            bfq = __builtin_bit_cast(short8, t);
        }
        // k: tile0 rows 8-15 = regs 4-7 -> Kl[px][8ch] (uint2 per lane, lh-half)
        {
            uint2 kk;
            kk.x = pack_bf_trunc(a0[4] + biasS[8 + 4 * lh + 0], a0[5] + biasS[8 + 4 * lh + 1]);
            kk.y = pack_bf_trunc(a0[6] + biasS[8 + 4 * lh + 2], a0[7] + biasS[8 + 4 * lh + 3]);
            *(uint2*)&Kl[px * 8 + 4 * lh] = kk;
        }
        // v: tile0 rows 16-31 (regs 8-15) = ch 0-15; tile1 = ch 16-47;
        //    tile2 regs 0-7 = ch 48-63. Vs[ch][key px], chunk ^= (ch&15).
        #pragma unroll
        for (int reg = 8; reg < 16; reg++) {
            int ch = (reg & 3) + 8 * ((reg >> 2) - 2) + 4 * lh;
            Vs[ch * 128 + (((px >> 3) ^ (ch & 15)) << 3) + (px & 7)] =
                trunc_bf(a0[reg] + biasS[16 + ch]);
        }
        #pragma unroll
        for (int reg = 0; reg < 16; reg++) {
            int ch = 16 + (reg & 3) + 8 * (reg >> 2) + 4 * lh;
            Vs[ch * 128 + (((px >> 3) ^ (ch & 15)) << 3) + (px & 7)] =
                trunc_bf(a1[reg] + biasS[16 + ch]);
        }
        #pragma unroll
        for (int reg = 0; reg < 8; reg++) {
            int ch = 48 + (reg & 3) + 8 * (reg >> 2) + 4 * lh;
            Vs[ch * 128 + (((px >> 3) ^ (ch & 15)) << 3) + (px & 7)] =
                trunc_bf(a2[reg] + biasS[16 + ch]);
        }
        __syncthreads();   // Kl/Vs visible to all waves
        // ---------------- attention (verified R7/R10 structure) ----------------
        float partial = 0.f;
        #pragma unroll
        for (int kg = 0; kg < 4; kg++) {
            short8 af = z8;
            if (lh == 0) af = *(const short8*)&Kl[(32 * kg + lr) * 8];
            floatx16 e = __builtin_amdgcn_mfma_f32_32x32x16_bf16(af, bfq, z16, 0, 0, 0);
            #pragma unroll
            for (int r = 0; r < 16; r++) {
                float p = exp2f(e[r]);   // L2E folded into q; no max-pass (|e| small)
                e[r] = p;
                partial += p;
            }
            #pragma unroll
            for (int cc = 0; cc < 2; cc++) {
                unsigned Y0 = pack_bf_trunc(e[8*cc+0], e[8*cc+1]);
                unsigned Y1 = pack_bf_trunc(e[8*cc+2], e[8*cc+3]);
                unsigned Y2 = pack_bf_trunc(e[8*cc+4], e[8*cc+5]);
                unsigned Y3 = pack_bf_trunc(e[8*cc+6], e[8*cc+7]);
                unsigned pY0 = __shfl_xor(Y0, 32);
                unsigned pY1 = __shfl_xor(Y1, 32);
                unsigned pY2 = __shfl_xor(Y2, 32);
                unsigned pY3 = __shfl_xor(Y3, 32);
                uvec4 t;
                t.x = lh ? pY2 : Y0;
                t.y = lh ? pY3 : Y1;
                t.z = lh ? Y2  : pY0;
                t.w = lh ? Y3  : pY1;
                short8 pf = __builtin_bit_cast(short8, t);
                int ks = 2 * kg + cc;
                int cp = ((2 * ks + lh) ^ (lr & 15)) * 8;
                short8 v0 = *(const short8*)&Vs[lr * 128 + cp];
                short8 v1 = *(const short8*)&Vs[(32 + lr) * 128 + cp];
                if (side == 0) {
                    oh0 = __builtin_amdgcn_mfma_f32_32x32x16_bf16(v0, pf, oh0, 0, 0, 0);
                    oh1 = __builtin_amdgcn_mfma_f32_32x32x16_bf16(v1, pf, oh1, 0, 0, 0);
                } else {
                    ov0 = __builtin_amdgcn_mfma_f32_32x32x16_bf16(v0, pf, ov0, 0, 0, 0);
                    ov1 = __builtin_amdgcn_mfma_f32_32x32x16_bf16(v1, pf, ov1, 0, 0, 0);
                }
            }
        }
        float ssum = partial + __shfl_xor(partial, 32);
        if (side == 0) ssA = ssum; else ssB = ssum;
    }

    __syncthreads();   // re-converge waves: adjacent 128B out-stores coalesce

    const float g  = gamma[0];
    const float g0 = g / ssA, g1 = g / ssB;
    #pragma unroll
    for (int reg = 0; reg < 16; reg++) {
        int ch = (reg & 3) + 8 * (reg >> 2) + 4 * lh;
        int idx0 = (bh * 64 + ch) * HW + y * 128 + px;
        int idx1 = (bh * 64 + 32 + ch) * HW + y * 128 + px;
        out[idx0] = g0 * oh0[reg] + g1 * ov0[reg] + xin[idx0];
        out[idx1] = g0 * oh1[reg] + g1 * ov1[reg] + xin[idx1];
    }
}

extern "C" void kernel_launch(void* const* d_in, const int* in_sizes, int n_in,
                              void* d_out, int out_size, void* d_ws, size_t ws_size,
                              hipStream_t stream) {
    const float* x     = (const float*)d_in[0];
    const float* Wq    = (const float*)d_in[1];
    const float* bq    = (const float*)d_in[2];
    const float* Wk    = (const float*)d_in[3];
    const float* bk    = (const float*)d_in[4];
    const float* Wv    = (const float*)d_in[5];
    const float* bv    = (const float*)d_in[6];
    const float* gamma = (const float*)d_in[7];
    float* out = (float*)d_out;

    unsigned short* Wb  = (unsigned short*)d_ws;
    unsigned short* xt  = Wb + 320 * 256;      // 32MB
    unsigned short* xtc = xt + 4 * HW * 256;   // 32MB, pixel-transposed copy

    cast_xt_kernel<<<dim3(256, 4, 4), 256, 0, stream>>>(x, Wq, Wk, Wv, Wb, xt);
    tpx_kernel<<<dim3(128, 4), 256, 0, stream>>>(xt, xtc);
    fused_kernel<<<dim3(2048), 256, 0, stream>>>(Wb, xt, xtc, bq, bk, bv, x, gamma, out);
}